// Round 2
// baseline (1270.178 us; speedup 1.0000x reference)
//
#include <hip/hip_runtime.h>
#include <hip/hip_bf16.h>

// WeisfeilerLehman: labels0 = argmax(x, -1); 3x ordered polynomial hash over edges.
// All arithmetic mod 2^32 (uint32 wrap) == reference int64 truncated to int32.

#define WL_D 128

__global__ void wl_argmax(const float* __restrict__ x, unsigned* __restrict__ lab0, int n) {
    int wave = (int)((blockIdx.x * blockDim.x + threadIdx.x) >> 6);
    int lane = threadIdx.x & 63;
    if (wave >= n) return;
    const float* xr = x + (size_t)wave * WL_D;
    float v0 = xr[lane];
    float v1 = xr[lane + 64];
    float bv; int bi;
    if (v1 > v0) { bv = v1; bi = lane + 64; } else { bv = v0; bi = lane; }
    #pragma unroll
    for (int off = 32; off > 0; off >>= 1) {
        float ov = __shfl_down(bv, off, 64);
        int   oi = __shfl_down(bi, off, 64);
        if (ov > bv || (ov == bv && oi < bi)) { bv = ov; bi = oi; }
    }
    if (lane == 0) lab0[wave] = (unsigned)bi;
}

__global__ void wl_deg(const int* __restrict__ ei, unsigned* __restrict__ deg, int E) {
    int e = blockIdx.x * blockDim.x + threadIdx.x;
    if (e >= E) return;
    atomicAdd(&deg[ei[e]], 1u);
}

// Exclusive scan, two-level. scan1: per-block (512) exclusive scan + block sums.
__global__ void wl_scan1(const unsigned* __restrict__ in, unsigned* __restrict__ out,
                         unsigned* __restrict__ bsums, int n) {
    __shared__ unsigned tmp[512];
    int i = blockIdx.x * 512 + threadIdx.x;
    unsigned v = (i < n) ? in[i] : 0u;
    tmp[threadIdx.x] = v;
    __syncthreads();
    for (int off = 1; off < 512; off <<= 1) {
        unsigned t = (threadIdx.x >= (unsigned)off) ? tmp[threadIdx.x - off] : 0u;
        __syncthreads();
        tmp[threadIdx.x] += t;
        __syncthreads();
    }
    if (i < n) out[i] = tmp[threadIdx.x] - v;   // exclusive
    if (threadIdx.x == 511) bsums[blockIdx.x] = tmp[511];
}

// scan2: single block exclusive scan of block sums (nb <= 1024)
__global__ void wl_scan2(unsigned* __restrict__ bsums, int nb) {
    __shared__ unsigned tmp[1024];
    int t = threadIdx.x;
    unsigned v = (t < nb) ? bsums[t] : 0u;
    tmp[t] = v;
    __syncthreads();
    for (int off = 1; off < 1024; off <<= 1) {
        unsigned s = (t >= off) ? tmp[t - off] : 0u;
        __syncthreads();
        tmp[t] += s;
        __syncthreads();
    }
    if (t < nb) bsums[t] = tmp[t] - v;          // exclusive
}

__global__ void wl_scan3(unsigned* __restrict__ out, const unsigned* __restrict__ bsums, int n) {
    int i = blockIdx.x * 512 + threadIdx.x;
    if (i < n) out[i] += bsums[blockIdx.x];
}

__global__ void wl_scatter(const int* __restrict__ ei, const unsigned* __restrict__ row_start,
                           unsigned* __restrict__ cursor, unsigned* __restrict__ csr_eid, int E) {
    int e = blockIdx.x * blockDim.x + threadIdx.x;
    if (e >= E) return;
    int r = ei[e];
    unsigned slot = atomicAdd(&cursor[r], 1u);
    csr_eid[row_start[r] + slot] = (unsigned)e;
}

// Per EDGE: rank = #{edges in same row with smaller edge id}; exp = deg-1-rank;
// pw[e] = 31^exp mod 2^32 (binary powering).
// 3.2M threads x ~deg loads each; row segments are shared by deg threads -> L1/L2 hits.
__global__ void wl_rank_edge(const int* __restrict__ ei, const unsigned* __restrict__ row_start,
                             const unsigned* __restrict__ deg, const unsigned* __restrict__ csr_eid,
                             unsigned* __restrict__ pw, int E) {
    int e = blockIdx.x * blockDim.x + threadIdx.x;
    if (e >= E) return;
    int r = ei[e];
    unsigned start = row_start[r];
    unsigned d = deg[r];
    unsigned me = (unsigned)e;
    unsigned rank = 0;
    const unsigned* seg = csr_eid + start;
    for (unsigned i = 0; i < d; ++i)
        rank += (seg[i] < me) ? 1u : 0u;
    unsigned ex = d - 1u - rank;
    unsigned p = 1u, b = 31u;
    while (ex) { if (ex & 1u) p *= b; b *= b; ex >>= 1u; }
    pw[e] = p;
}

__global__ void wl_propagate(const int* __restrict__ ei, const unsigned* __restrict__ pw,
                             const unsigned* __restrict__ lin, unsigned* __restrict__ lout, int E) {
    int e = blockIdx.x * blockDim.x + threadIdx.x;
    if (e >= E) return;
    int r = ei[e];
    int c = ei[E + e];
    unsigned v = lin[c] * pw[e];
    atomicAdd(&lout[r], v);   // wraps mod 2^32 — order-independent
}

__global__ void wl_write_out(const unsigned* __restrict__ l0, const unsigned* __restrict__ l1,
                             const unsigned* __restrict__ l2, const unsigned* __restrict__ l3,
                             int* __restrict__ out, int n) {
    int i = blockIdx.x * blockDim.x + threadIdx.x;
    if (i >= n) return;
    int a0 = (int)l0[i], a1 = (int)l1[i], a2 = (int)l2[i], a3 = (int)l3[i];
    out[i]         = a3;   // labels3 (final)
    out[n + i]     = a0;   // labels0
    out[2 * n + i] = a1;   // labels1
    out[3 * n + i] = a2;   // labels2
    out[4 * n + i] = a3;   // labels3
}

extern "C" void kernel_launch(void* const* d_in, const int* in_sizes, int n_in,
                              void* d_out, int out_size, void* d_ws, size_t ws_size,
                              hipStream_t stream) {
    const float* x  = (const float*)d_in[0];
    const int*   ei = (const int*)d_in[1];      // int inputs arrive as int32
    int* out = (int*)d_out;

    const int N = in_sizes[0] / WL_D;
    const int E = in_sizes[1] / 2;

    // workspace layout (uint32 units)
    unsigned* ws   = (unsigned*)d_ws;
    unsigned* lab0 = ws;               // N
    unsigned* lab1 = lab0 + N;         // N
    unsigned* lab2 = lab1 + N;         // N
    unsigned* lab3 = lab2 + N;         // N
    unsigned* deg  = lab3 + N;         // N
    unsigned* cur  = deg + N;          // N
    unsigned* rs   = cur + N;          // N   (row_start, exclusive scan of deg)
    unsigned* bs   = rs + N;           // 1024 (block sums)
    unsigned* csr  = bs + 1024;        // E   (edge ids grouped by row, unordered)
    unsigned* pw   = csr + E;          // E   (31^exp per edge)

    // zero: lab0..cur  (lab1-3 are atomic accumulators, deg/cur histograms)
    hipMemsetAsync(ws, 0, (size_t)6 * N * sizeof(unsigned), stream);

    const int BT = 256;
    int gridN  = (N + BT - 1) / BT;
    int gridE  = (E + BT - 1) / BT;
    int gridAM = (N + 3) / 4;                 // 4 waves per block, 1 wave/node
    int nb     = (N + 511) / 512;             // scan blocks (<=1024 supported)

    wl_argmax<<<gridAM, BT, 0, stream>>>(x, lab0, N);
    wl_deg<<<gridE, BT, 0, stream>>>(ei, deg, E);
    wl_scan1<<<nb, 512, 0, stream>>>(deg, rs, bs, N);
    wl_scan2<<<1, 1024, 0, stream>>>(bs, nb);
    wl_scan3<<<nb, 512, 0, stream>>>(rs, bs, N);
    wl_scatter<<<gridE, BT, 0, stream>>>(ei, rs, cur, csr, E);
    wl_rank_edge<<<gridE, BT, 0, stream>>>(ei, rs, deg, csr, pw, E);

    wl_propagate<<<gridE, BT, 0, stream>>>(ei, pw, lab0, lab1, E);
    wl_propagate<<<gridE, BT, 0, stream>>>(ei, pw, lab1, lab2, E);
    wl_propagate<<<gridE, BT, 0, stream>>>(ei, pw, lab2, lab3, E);

    wl_write_out<<<gridN, BT, 0, stream>>>(lab0, lab1, lab2, lab3, out, N);
}

// Round 3
// 594.594 us; speedup vs baseline: 2.1362x; 2.1362x over previous
//
#include <hip/hip_runtime.h>
#include <hip/hip_bf16.h>

// WeisfeilerLehman: labels0 = argmax(x, -1); 3x ordered polynomial hash over edges.
// All arithmetic mod 2^32 (uint32 wrap) == reference int64 truncated to int32.
// R3: ordered column-CSR via in-wave shuffle sort; atomic-free wave-per-row Horner.

#define WL_D 128

__global__ void wl_argmax(const float* __restrict__ x, unsigned* __restrict__ lab0, int n) {
    int wave = (int)((blockIdx.x * blockDim.x + threadIdx.x) >> 6);
    int lane = threadIdx.x & 63;
    if (wave >= n) return;
    const float* xr = x + (size_t)wave * WL_D;
    float v0 = xr[lane];
    float v1 = xr[lane + 64];
    float bv; int bi;
    if (v1 > v0) { bv = v1; bi = lane + 64; } else { bv = v0; bi = lane; }
    #pragma unroll
    for (int off = 32; off > 0; off >>= 1) {
        float ov = __shfl_down(bv, off, 64);
        int   oi = __shfl_down(bi, off, 64);
        if (ov > bv || (ov == bv && oi < bi)) { bv = ov; bi = oi; }
    }
    if (lane == 0) lab0[wave] = (unsigned)bi;
}

__global__ void wl_deg(const int* __restrict__ ei, unsigned* __restrict__ deg, int E) {
    int e = blockIdx.x * blockDim.x + threadIdx.x;
    if (e >= E) return;
    atomicAdd(&deg[ei[e]], 1u);
}

// Exclusive scan, two-level.
__global__ void wl_scan1(const unsigned* __restrict__ in, unsigned* __restrict__ out,
                         unsigned* __restrict__ bsums, int n) {
    __shared__ unsigned tmp[512];
    int i = blockIdx.x * 512 + threadIdx.x;
    unsigned v = (i < n) ? in[i] : 0u;
    tmp[threadIdx.x] = v;
    __syncthreads();
    for (int off = 1; off < 512; off <<= 1) {
        unsigned t = (threadIdx.x >= (unsigned)off) ? tmp[threadIdx.x - off] : 0u;
        __syncthreads();
        tmp[threadIdx.x] += t;
        __syncthreads();
    }
    if (i < n) out[i] = tmp[threadIdx.x] - v;   // exclusive
    if (threadIdx.x == 511) bsums[blockIdx.x] = tmp[511];
}

__global__ void wl_scan2(unsigned* __restrict__ bsums, int nb) {
    __shared__ unsigned tmp[1024];
    int t = threadIdx.x;
    unsigned v = (t < nb) ? bsums[t] : 0u;
    tmp[t] = v;
    __syncthreads();
    for (int off = 1; off < 1024; off <<= 1) {
        unsigned s = (t >= off) ? tmp[t - off] : 0u;
        __syncthreads();
        tmp[t] += s;
        __syncthreads();
    }
    if (t < nb) bsums[t] = tmp[t] - v;          // exclusive
}

__global__ void wl_scan3(unsigned* __restrict__ out, const unsigned* __restrict__ bsums, int n) {
    int i = blockIdx.x * 512 + threadIdx.x;
    if (i < n) out[i] += bsums[blockIdx.x];
}

__global__ void wl_scatter(const int* __restrict__ ei, const unsigned* __restrict__ row_start,
                           unsigned* __restrict__ cursor, unsigned* __restrict__ csr, int E) {
    int e = blockIdx.x * blockDim.x + threadIdx.x;
    if (e >= E) return;
    int r = ei[e];
    unsigned slot = atomicAdd(&cursor[r], 1u);
    csr[row_start[r] + slot] = (unsigned)e;
}

// One wave per row. Lanes hold the row's (unordered) edge ids in registers,
// compute edge-order rank via all-pairs shuffle compare (ids unique), gather
// each edge's col, then overwrite the segment IN PLACE with cols in edge order.
// Safe: every lane's loads are in registers before the (lockstep) store issues.
__global__ void wl_sort_rows(const int* __restrict__ ei, const unsigned* __restrict__ rs,
                             const unsigned* __restrict__ deg, unsigned* __restrict__ csr,
                             int n, int E) {
    int r = (int)((blockIdx.x * blockDim.x + threadIdx.x) >> 6);
    int lane = threadIdx.x & 63;
    if (r >= n) return;
    unsigned start = rs[r], d = deg[r];
    if (d == 0) return;
    if (d <= 64) {
        unsigned eid = (lane < (int)d) ? csr[start + lane] : 0xFFFFFFFFu;
        unsigned col = (lane < (int)d) ? (unsigned)ei[(size_t)E + eid] : 0u;
        unsigned rank = 0;
        for (unsigned j = 0; j < d; ++j) {
            unsigned other = __shfl(eid, (int)j, 64);
            rank += (other < eid) ? 1u : 0u;
        }
        if (lane < (int)d) csr[start + rank] = col;   // col in edge-order slot
    } else {
        // rare fallback: d in (64, 512]
        const int K = 8;
        unsigned eidR[K], colR[K], rankR[K];
        int kk = (int)((d + 63u) >> 6);
        #pragma unroll
        for (int k = 0; k < K; ++k) {
            int j = lane + 64 * k;
            eidR[k] = (k < kk && j < (int)d) ? csr[start + j] : 0xFFFFFFFFu;
        }
        #pragma unroll
        for (int k = 0; k < K; ++k) {
            int j = lane + 64 * k;
            colR[k] = (k < kk && j < (int)d) ? (unsigned)ei[(size_t)E + eidR[k]] : 0u;
            rankR[k] = 0;
        }
        for (int k2 = 0; k2 < kk; ++k2) {
            for (int l = 0; l < 64; ++l) {
                unsigned other = __shfl(eidR[k2], l, 64);
                #pragma unroll
                for (int k = 0; k < K; ++k)
                    rankR[k] += (other < eidR[k]) ? 1u : 0u;   // MAX sentinel never counts
            }
        }
        #pragma unroll
        for (int k = 0; k < K; ++k) {
            int j = lane + 64 * k;
            if (k < kk && j < (int)d) csr[start + rankR[k]] = colR[k];
        }
    }
}

// One wave per row: new[r] = sum_j lab[col_j] * 31^(d-1-j)  (mod 2^32).
// Coalesced segment read; lab gather hits L2 (400 KB table); no atomics.
__global__ void wl_prop(const unsigned* __restrict__ col_csr, const unsigned* __restrict__ rs,
                        const unsigned* __restrict__ deg, const unsigned* __restrict__ lin,
                        unsigned* __restrict__ lout, int n) {
    int r = (int)((blockIdx.x * blockDim.x + threadIdx.x) >> 6);
    int lane = threadIdx.x & 63;
    if (r >= n) return;
    unsigned start = rs[r], d = deg[r];
    unsigned acc = 0;
    for (unsigned j = (unsigned)lane; j < d; j += 64u) {
        unsigned ex = d - 1u - j;
        unsigned p = 1u, b = 31u;
        while (ex) { if (ex & 1u) p *= b; b *= b; ex >>= 1u; }
        acc += lin[col_csr[start + j]] * p;
    }
    #pragma unroll
    for (int off = 32; off > 0; off >>= 1) acc += __shfl_xor(acc, off, 64);
    if (lane == 0) lout[r] = acc;
}

__global__ void wl_write_out(const unsigned* __restrict__ l0, const unsigned* __restrict__ l1,
                             const unsigned* __restrict__ l2, const unsigned* __restrict__ l3,
                             int* __restrict__ out, int n) {
    int i = blockIdx.x * blockDim.x + threadIdx.x;
    if (i >= n) return;
    int a0 = (int)l0[i], a1 = (int)l1[i], a2 = (int)l2[i], a3 = (int)l3[i];
    out[i]         = a3;   // labels3 (final)
    out[n + i]     = a0;   // labels0
    out[2 * n + i] = a1;   // labels1
    out[3 * n + i] = a2;   // labels2
    out[4 * n + i] = a3;   // labels3
}

extern "C" void kernel_launch(void* const* d_in, const int* in_sizes, int n_in,
                              void* d_out, int out_size, void* d_ws, size_t ws_size,
                              hipStream_t stream) {
    const float* x  = (const float*)d_in[0];
    const int*   ei = (const int*)d_in[1];
    int* out = (int*)d_out;

    const int N = in_sizes[0] / WL_D;
    const int E = in_sizes[1] / 2;

    // workspace layout (uint32 units); deg+cur first so one memset covers them
    unsigned* ws   = (unsigned*)d_ws;
    unsigned* deg  = ws;               // N  (needs zero)
    unsigned* cur  = deg + N;          // N  (needs zero)
    unsigned* lab0 = cur + N;          // N
    unsigned* lab1 = lab0 + N;         // N
    unsigned* lab2 = lab1 + N;         // N
    unsigned* lab3 = lab2 + N;         // N
    unsigned* rs   = lab3 + N;         // N
    unsigned* bs   = rs + N;           // 1024
    unsigned* csr  = bs + 1024;        // E  (in: edge ids by row; after sort: cols in edge order)

    hipMemsetAsync(ws, 0, (size_t)2 * N * sizeof(unsigned), stream);

    const int BT = 256;
    int gridN  = (N + BT - 1) / BT;
    int gridE  = (E + BT - 1) / BT;
    int gridW  = (N + 3) / 4;                 // wave-per-row kernels (4 waves/block)
    int nb     = (N + 511) / 512;

    wl_argmax<<<gridW, BT, 0, stream>>>(x, lab0, N);
    wl_deg<<<gridE, BT, 0, stream>>>(ei, deg, E);
    wl_scan1<<<nb, 512, 0, stream>>>(deg, rs, bs, N);
    wl_scan2<<<1, 1024, 0, stream>>>(bs, nb);
    wl_scan3<<<nb, 512, 0, stream>>>(rs, bs, N);
    wl_scatter<<<gridE, BT, 0, stream>>>(ei, rs, cur, csr, E);
    wl_sort_rows<<<gridW, BT, 0, stream>>>(ei, rs, deg, csr, N, E);

    wl_prop<<<gridW, BT, 0, stream>>>(csr, rs, deg, lab0, lab1, N);
    wl_prop<<<gridW, BT, 0, stream>>>(csr, rs, deg, lab1, lab2, N);
    wl_prop<<<gridW, BT, 0, stream>>>(csr, rs, deg, lab2, lab3, N);

    wl_write_out<<<gridN, BT, 0, stream>>>(lab0, lab1, lab2, lab3, out, N);
}

// Round 4
// 391.305 us; speedup vs baseline: 3.2460x; 1.5195x over previous
//
#include <hip/hip_runtime.h>
#include <hip/hip_bf16.h>

// WeisfeilerLehman: labels0 = argmax(x, -1); 3x ordered polynomial hash over edges.
// All arithmetic mod 2^32 (uint32 wrap) == reference int64 truncated to int32.
// R4: stable 2-level bucket sort (no global atomics) -> ordered col-CSR;
//     wave-per-row Horner props. Assumes N <= 2^24 and nbuckets <= 512 (N <= 131072).

#define WL_D 128
#define CHUNK 4096          // edges per MSD chunk
#define BROWS 256           // rows per bucket (rl = row & 255, bucket = row >> 8)

__global__ void wl_argmax(const float* __restrict__ x, unsigned* __restrict__ lab0, int n) {
    int wave = (int)((blockIdx.x * blockDim.x + threadIdx.x) >> 6);
    int lane = threadIdx.x & 63;
    if (wave >= n) return;
    const float* xr = x + (size_t)wave * WL_D;
    float v0 = xr[lane];
    float v1 = xr[lane + 64];
    float bv; int bi;
    if (v1 > v0) { bv = v1; bi = lane + 64; } else { bv = v0; bi = lane; }
    #pragma unroll
    for (int off = 32; off > 0; off >>= 1) {
        float ov = __shfl_down(bv, off, 64);
        int   oi = __shfl_down(bi, off, 64);
        if (ov > bv || (ov == bv && oi < bi)) { bv = ov; bi = oi; }
    }
    if (lane == 0) lab0[wave] = (unsigned)bi;
}

// ---- two-level exclusive scan (in-place safe: each block touches only its range) ----
__global__ void wl_scan1(const unsigned* __restrict__ in, unsigned* __restrict__ out,
                         unsigned* __restrict__ bsums, int n) {
    __shared__ unsigned tmp[512];
    int i = blockIdx.x * 512 + threadIdx.x;
    unsigned v = (i < n) ? in[i] : 0u;
    tmp[threadIdx.x] = v;
    __syncthreads();
    for (int off = 1; off < 512; off <<= 1) {
        unsigned t = (threadIdx.x >= (unsigned)off) ? tmp[threadIdx.x - off] : 0u;
        __syncthreads();
        tmp[threadIdx.x] += t;
        __syncthreads();
    }
    if (i < n) out[i] = tmp[threadIdx.x] - v;   // exclusive
    if (threadIdx.x == 511) bsums[blockIdx.x] = tmp[511];
}

__global__ void wl_scan2(unsigned* __restrict__ bsums, int nb) {
    __shared__ unsigned tmp[1024];
    int t = threadIdx.x;
    unsigned v = (t < nb) ? bsums[t] : 0u;
    tmp[t] = v;
    __syncthreads();
    for (int off = 1; off < 1024; off <<= 1) {
        unsigned s = (t >= off) ? tmp[t - off] : 0u;
        __syncthreads();
        tmp[t] += s;
        __syncthreads();
    }
    if (t < nb) bsums[t] = tmp[t] - v;          // exclusive
}

__global__ void wl_scan3(unsigned* __restrict__ out, const unsigned* __restrict__ bsums, int n) {
    int i = blockIdx.x * 512 + threadIdx.x;
    if (i < n) out[i] += bsums[blockIdx.x];
}

// ---- MSD pass 1: per-chunk histogram over buckets, layout hist[bucket][chunk] ----
__global__ void wl_msd_hist(const int* __restrict__ ei, unsigned* __restrict__ hist,
                            int E, int nchunks, int nbuckets) {
    __shared__ unsigned h[512];
    int c = blockIdx.x;
    for (int i = threadIdx.x; i < nbuckets; i += 256) h[i] = 0;
    __syncthreads();
    int base = c * CHUNK;
    for (int i = threadIdx.x; i < CHUNK; i += 256) {
        int e = base + i;
        if (e < E) atomicAdd(&h[((unsigned)ei[e]) >> 8], 1u);   // LDS atomic
    }
    __syncthreads();
    for (int b = threadIdx.x; b < nbuckets; b += 256)
        hist[(size_t)b * nchunks + c] = h[b];
}

// ---- MSD pass 2: stable scatter of packed (row&255)<<24 | col into bucket order ----
__global__ void wl_msd_scatter(const int* __restrict__ ei, const unsigned* __restrict__ chunkoff,
                               unsigned* __restrict__ buf, int E, int nchunks, int nbuckets) {
    __shared__ unsigned run[512];
    __shared__ unsigned whist[4][512];
    int c = blockIdx.x;
    int t = threadIdx.x;
    int lane = t & 63, w = t >> 6;
    for (int i = t; i < nbuckets; i += 256) run[i] = 0;
    int base = c * CHUNK;
    const int nbatch = CHUNK / 256;
    for (int batch = 0; batch < nbatch; ++batch) {
        int e = base + batch * 256 + t;
        bool act = (e < E);
        unsigned r   = act ? (unsigned)ei[e] : 0xFFFFFFFFu;
        unsigned col = act ? (unsigned)ei[(size_t)E + e] : 0u;
        unsigned v = r >> 8;                      // bucket; inactive -> 0xFFFFFF (never valid)
        // rank among earlier lanes with same bucket (stable, in-wave)
        unsigned before = 0, total = 0;
        for (int j = 0; j < 64; ++j) {
            unsigned o  = __shfl(v, j, 64);
            unsigned eq = (o == v) ? 1u : 0u;
            total += eq;
            if (j < lane) before += eq;
        }
        __syncthreads();                           // prior batch done with whist/run
        for (int i = t; i < 4 * 512; i += 256) ((unsigned*)whist)[i] = 0;
        __syncthreads();
        if (act && before == 0) whist[w][v] = total;
        __syncthreads();
        unsigned brank = before, btot = 0;
        if (act) {
            #pragma unroll
            for (int w2 = 0; w2 < 4; ++w2) {
                unsigned hv = whist[w2][v];
                if (w2 < w) brank += hv;
                btot += hv;
            }
        }
        unsigned basec = act ? run[v] : 0u;
        __syncthreads();
        if (act && brank == 0) run[v] = basec + btot;
        if (act) {
            unsigned gbase = chunkoff[(size_t)v * nchunks + c];
            buf[gbase + basec + brank] = ((r & 255u) << 24) | col;
        }
    }
}

// ---- per-bucket stable counting sort by row_local; emits rs, deg, ordered col-CSR ----
__global__ void wl_bucket_sort(const unsigned* __restrict__ buf, const unsigned* __restrict__ chunkoff,
                               unsigned* __restrict__ csr, unsigned* __restrict__ rs_g,
                               unsigned* __restrict__ deg_g, int N, int E, int nchunks, int nbuckets) {
    __shared__ unsigned hist[256], off[256], run[256];
    __shared__ unsigned whist[4][256];
    int b = blockIdx.x;
    int t = threadIdx.x;
    int lane = t & 63, w = t >> 6;
    unsigned start = chunkoff[(size_t)b * nchunks];
    unsigned end   = (b + 1 < nbuckets) ? chunkoff[(size_t)(b + 1) * nchunks] : (unsigned)E;
    unsigned len   = end - start;
    hist[t] = 0; run[t] = 0;
    __syncthreads();
    // pass 1: row_local histogram
    for (unsigned i = t; i < len; i += 256)
        atomicAdd(&hist[buf[start + i] >> 24], 1u);
    __syncthreads();
    // inclusive scan -> exclusive offsets
    unsigned hv = hist[t];
    off[t] = hv;
    __syncthreads();
    for (int o = 1; o < 256; o <<= 1) {
        unsigned s = (t >= o) ? off[t - o] : 0u;
        __syncthreads();
        off[t] += s;
        __syncthreads();
    }
    unsigned excl = off[t] - hv;
    __syncthreads();
    off[t] = excl;
    int row = b * BROWS + t;
    if (row < N) { rs_g[row] = start + excl; deg_g[row] = hv; }
    __syncthreads();
    // pass 2: stable scatter by row_local into final CSR slice
    unsigned nb2 = (len + 255u) / 256u;
    for (unsigned batch = 0; batch < nb2; ++batch) {
        unsigned i = batch * 256u + t;
        bool act = (i < len);
        unsigned p = act ? buf[start + i] : 0u;
        unsigned v = act ? (p >> 24) : 0xFFFFFFFFu;   // sentinel outside valid rl range
        unsigned col = p & 0xFFFFFFu;
        unsigned before = 0, total = 0;
        for (int j = 0; j < 64; ++j) {
            unsigned o  = __shfl(v, j, 64);
            unsigned eq = (o == v) ? 1u : 0u;
            total += eq;
            if (j < lane) before += eq;
        }
        __syncthreads();
        for (int k = t; k < 4 * 256; k += 256) ((unsigned*)whist)[k] = 0;
        __syncthreads();
        if (act && before == 0) whist[w][v] = total;
        __syncthreads();
        unsigned brank = before, btot = 0;
        if (act) {
            #pragma unroll
            for (int w2 = 0; w2 < 4; ++w2) {
                unsigned x = whist[w2][v];
                if (w2 < w) brank += x;
                btot += x;
            }
        }
        unsigned basec = act ? run[v] : 0u;
        __syncthreads();
        if (act && brank == 0) run[v] = basec + btot;
        if (act) csr[start + off[v] + basec + brank] = col;
    }
}

// One wave per row: new[r] = sum_j lab[col_j] * 31^(d-1-j)  (mod 2^32).
__global__ void wl_prop(const unsigned* __restrict__ col_csr, const unsigned* __restrict__ rs,
                        const unsigned* __restrict__ deg, const unsigned* __restrict__ lin,
                        unsigned* __restrict__ lout, int n) {
    int r = (int)((blockIdx.x * blockDim.x + threadIdx.x) >> 6);
    int lane = threadIdx.x & 63;
    if (r >= n) return;
    unsigned start = rs[r], d = deg[r];
    unsigned acc = 0;
    for (unsigned j = (unsigned)lane; j < d; j += 64u) {
        unsigned ex = d - 1u - j;
        unsigned p = 1u, b = 31u;
        while (ex) { if (ex & 1u) p *= b; b *= b; ex >>= 1u; }
        acc += lin[col_csr[start + j]] * p;
    }
    #pragma unroll
    for (int off = 32; off > 0; off >>= 1) acc += __shfl_xor(acc, off, 64);
    if (lane == 0) lout[r] = acc;
}

__global__ void wl_write_out(const unsigned* __restrict__ l0, const unsigned* __restrict__ l1,
                             const unsigned* __restrict__ l2, const unsigned* __restrict__ l3,
                             int* __restrict__ out, int n) {
    int i = blockIdx.x * blockDim.x + threadIdx.x;
    if (i >= n) return;
    int a0 = (int)l0[i], a1 = (int)l1[i], a2 = (int)l2[i], a3 = (int)l3[i];
    out[i]         = a3;   // labels3 (final)
    out[n + i]     = a0;   // labels0
    out[2 * n + i] = a1;   // labels1
    out[3 * n + i] = a2;   // labels2
    out[4 * n + i] = a3;   // labels3
}

extern "C" void kernel_launch(void* const* d_in, const int* in_sizes, int n_in,
                              void* d_out, int out_size, void* d_ws, size_t ws_size,
                              hipStream_t stream) {
    const float* x  = (const float*)d_in[0];
    const int*   ei = (const int*)d_in[1];
    int* out = (int*)d_out;

    const int N = in_sizes[0] / WL_D;
    const int E = in_sizes[1] / 2;
    const int nchunks  = (E + CHUNK - 1) / CHUNK;
    const int nbuckets = (N + BROWS - 1) / BROWS;
    const int L = nbuckets * nchunks;          // scan length (<= 524288)

    // workspace layout (uint32 units) — everything written before read, no memset
    unsigned* ws   = (unsigned*)d_ws;
    unsigned* lab0 = ws;               // N
    unsigned* lab1 = lab0 + N;         // N
    unsigned* lab2 = lab1 + N;         // N
    unsigned* lab3 = lab2 + N;         // N
    unsigned* rs   = lab3 + N;         // N
    unsigned* deg  = rs + N;           // N
    unsigned* bs   = deg + N;          // 1024
    unsigned* hist = bs + 1024;        // L   (in-place scanned -> chunkoff)
    unsigned* buf  = hist + L;         // E   (bucket-ordered packed (rl<<24)|col)
    unsigned* csr  = buf + E;          // E   (final: cols in edge order per row)

    const int BT = 256;
    int gridN = (N + BT - 1) / BT;
    int gridW = (N + 3) / 4;                   // wave-per-row kernels
    int nb    = (L + 511) / 512;

    wl_argmax<<<gridW, BT, 0, stream>>>(x, lab0, N);

    wl_msd_hist<<<nchunks, BT, 0, stream>>>(ei, hist, E, nchunks, nbuckets);
    wl_scan1<<<nb, 512, 0, stream>>>(hist, hist, bs, L);
    wl_scan2<<<1, 1024, 0, stream>>>(bs, nb);
    wl_scan3<<<nb, 512, 0, stream>>>(hist, bs, L);
    wl_msd_scatter<<<nchunks, BT, 0, stream>>>(ei, hist, buf, E, nchunks, nbuckets);
    wl_bucket_sort<<<nbuckets, BT, 0, stream>>>(buf, hist, csr, rs, deg, N, E, nchunks, nbuckets);

    wl_prop<<<gridW, BT, 0, stream>>>(csr, rs, deg, lab0, lab1, N);
    wl_prop<<<gridW, BT, 0, stream>>>(csr, rs, deg, lab1, lab2, N);
    wl_prop<<<gridW, BT, 0, stream>>>(csr, rs, deg, lab2, lab3, N);

    wl_write_out<<<gridN, BT, 0, stream>>>(lab0, lab1, lab2, lab3, out, N);
}

// Round 5
// 309.974 us; speedup vs baseline: 4.0977x; 1.2624x over previous
//
#include <hip/hip_runtime.h>
#include <hip/hip_bf16.h>

// WeisfeilerLehman: labels0 = argmax(x, -1); 3x ordered polynomial hash over edges.
// All arithmetic mod 2^32 (uint32 wrap) == reference int64 truncated to int32.
// R5: stable 2-level bucket sort with ballot-match ranks + wave-turn run counters
//     (no whist, no global atomics); BROWS=128 for 3 blocks/CU; scan3 folded away.

#define WL_D 128
#define CHUNK 4096          // edges per MSD chunk
#define BROWS 128           // rows per bucket; bucket = row >> 7, rl = row & 127
#define BBITS 7

constexpr unsigned cpow(unsigned b, unsigned e) {
    unsigned p = 1;
    while (e) { if (e & 1u) p *= b; b *= b; e >>= 1u; }
    return p;
}
constexpr unsigned cinv31() {           // Newton: inverse of 31 mod 2^32
    unsigned x = 1;
    for (int i = 0; i < 6; ++i) x *= 2u - 31u * x;
    return x;
}
constexpr unsigned INV31_64 = cpow(cinv31(), 64);   // 31^-64 mod 2^32

__device__ inline unsigned dpow31(unsigned e) {
    unsigned p = 1, b = 31u;
    while (e) { if (e & 1u) p *= b; b *= b; e >>= 1u; }
    return p;
}

// mask of lanes whose low BITS bits of v match mine (inactive lanes use a
// sentinel outside the valid key range so they never match active lanes)
template <int BITS>
__device__ inline unsigned long long match_key(unsigned v) {
    unsigned long long m = ~0ull;
    #pragma unroll
    for (int b = 0; b < BITS; ++b) {
        unsigned long long s = __ballot((v >> b) & 1u);
        m &= ((v >> b) & 1u) ? s : ~s;
    }
    return m;
}

__global__ void wl_argmax(const float* __restrict__ x, unsigned* __restrict__ lab0, int n) {
    int wave = (int)((blockIdx.x * blockDim.x + threadIdx.x) >> 6);
    int lane = threadIdx.x & 63;
    if (wave >= n) return;
    const float* xr = x + (size_t)wave * WL_D;
    float v0 = xr[lane];
    float v1 = xr[lane + 64];
    float bv; int bi;
    if (v1 > v0) { bv = v1; bi = lane + 64; } else { bv = v0; bi = lane; }
    #pragma unroll
    for (int off = 32; off > 0; off >>= 1) {
        float ov = __shfl_down(bv, off, 64);
        int   oi = __shfl_down(bi, off, 64);
        if (ov > bv || (ov == bv && oi < bi)) { bv = ov; bi = oi; }
    }
    if (lane == 0) lab0[wave] = (unsigned)bi;
}

// ---- two-level exclusive scan (1024-wide level 1) ----
__global__ void wl_scan1(const unsigned* __restrict__ in, unsigned* __restrict__ out,
                         unsigned* __restrict__ bsums, int n) {
    __shared__ unsigned tmp[1024];
    int i = blockIdx.x * 1024 + threadIdx.x;
    unsigned v = (i < n) ? in[i] : 0u;
    tmp[threadIdx.x] = v;
    __syncthreads();
    for (int off = 1; off < 1024; off <<= 1) {
        unsigned t = (threadIdx.x >= (unsigned)off) ? tmp[threadIdx.x - off] : 0u;
        __syncthreads();
        tmp[threadIdx.x] += t;
        __syncthreads();
    }
    if (i < n) out[i] = tmp[threadIdx.x] - v;   // exclusive within block
    if (threadIdx.x == 1023) bsums[blockIdx.x] = tmp[1023];
}

__global__ void wl_scan2(unsigned* __restrict__ bsums, int nb) {
    __shared__ unsigned tmp[1024];
    int t = threadIdx.x;
    unsigned v = (t < nb) ? bsums[t] : 0u;
    tmp[t] = v;
    __syncthreads();
    for (int off = 1; off < 1024; off <<= 1) {
        unsigned s = (t >= off) ? tmp[t - off] : 0u;
        __syncthreads();
        tmp[t] += s;
        __syncthreads();
    }
    if (t < nb) bsums[t] = tmp[t] - v;          // exclusive
}

// ---- MSD pass 1: per-chunk histogram over buckets, layout hist[bucket][chunk] ----
__global__ void wl_msd_hist(const int* __restrict__ ei, unsigned* __restrict__ hist,
                            int E, int nchunks, int nbuckets) {
    __shared__ unsigned h[1024];
    int c = blockIdx.x;
    for (int i = threadIdx.x; i < nbuckets; i += 256) h[i] = 0;
    __syncthreads();
    int base = c * CHUNK;
    for (int i = threadIdx.x; i < CHUNK; i += 256) {
        int e = base + i;
        if (e < E) atomicAdd(&h[((unsigned)ei[e]) >> BBITS], 1u);   // LDS atomic
    }
    __syncthreads();
    for (int b = threadIdx.x; b < nbuckets; b += 256)
        hist[(size_t)b * nchunks + c] = h[b];
}

// ---- MSD pass 2: stable scatter of packed (rl<<24)|col into bucket order ----
__global__ void wl_msd_scatter(const int* __restrict__ ei, const unsigned* __restrict__ choff,
                               const unsigned* __restrict__ bs, unsigned* __restrict__ buf,
                               int E, int nchunks, int nbuckets) {
    __shared__ unsigned run[1024];
    int c = blockIdx.x, t = threadIdx.x;
    int lane = t & 63, w = t >> 6;
    for (int i = t; i < nbuckets; i += 256) run[i] = 0;
    __syncthreads();
    int base = c * CHUNK;
    unsigned long long lmask = (1ull << lane) - 1ull;
    for (int batch = 0; batch < CHUNK / 256; ++batch) {
        int e = base + batch * 256 + t;
        bool act = (e < E);
        unsigned r   = act ? (unsigned)ei[e] : 0u;
        unsigned col = act ? (unsigned)ei[(size_t)E + e] : 0u;
        unsigned v = act ? (r >> BBITS) : 1023u;       // sentinel >= nbuckets
        unsigned long long m = match_key<10>(v);
        unsigned before = (unsigned)__popcll(m & lmask);
        unsigned total  = (unsigned)__popcll(m);
        int leader = __ffsll(m) - 1;
        unsigned base0 = 0;
        #pragma unroll
        for (int w2 = 0; w2 < 4; ++w2) {               // wave-ordered run update
            if (w == w2 && act && before == 0u) { base0 = run[v]; run[v] = base0 + total; }
            __syncthreads();
        }
        base0 = __shfl(base0, leader, 64);
        if (act) {
            size_t idx = (size_t)v * nchunks + c;
            unsigned g = choff[idx] + bs[idx >> 10];   // fold scan level-2 here
            buf[g + base0 + before] = ((r & (BROWS - 1u)) << 24) | col;
        }
    }
}

// ---- per-bucket stable counting sort by rl; emits rs, deg, ordered col-CSR ----
__global__ void wl_bucket_sort(const unsigned* __restrict__ buf, const unsigned* __restrict__ choff,
                               const unsigned* __restrict__ bs, unsigned* __restrict__ csr,
                               unsigned* __restrict__ rs_g, unsigned* __restrict__ deg_g,
                               int N, int E, int nchunks, int nbuckets) {
    __shared__ unsigned hist[BROWS], off[BROWS], run[BROWS];
    int b = blockIdx.x, t = threadIdx.x;
    int lane = t & 63, w = t >> 6;
    size_t i0 = (size_t)b * nchunks;
    unsigned start = choff[i0] + bs[i0 >> 10];
    unsigned end;
    if (b + 1 < nbuckets) { size_t i1 = (size_t)(b + 1) * nchunks; end = choff[i1] + bs[i1 >> 10]; }
    else end = (unsigned)E;
    unsigned len = end - start;
    if (t < BROWS) { hist[t] = 0u; run[t] = 0u; }
    __syncthreads();
    // pass 1: rl histogram
    for (unsigned i = t; i < len; i += 256u)
        atomicAdd(&hist[buf[start + i] >> 24], 1u);
    __syncthreads();
    // exclusive scan of hist
    unsigned hv = (t < BROWS) ? hist[t] : 0u;
    if (t < BROWS) off[t] = hv;
    __syncthreads();
    for (int o = 1; o < BROWS; o <<= 1) {
        unsigned s = (t < BROWS && t >= o) ? off[t - o] : 0u;
        __syncthreads();
        if (t < BROWS) off[t] += s;
        __syncthreads();
    }
    unsigned incl = (t < BROWS) ? off[t] : 0u;
    __syncthreads();
    if (t < BROWS) off[t] = incl - hv;
    int row = b * BROWS + t;
    if (t < BROWS && row < N) { rs_g[row] = start + (incl - hv); deg_g[row] = hv; }
    __syncthreads();
    // pass 2: stable scatter by rl into final CSR slice
    unsigned long long lmask = (1ull << lane) - 1ull;
    unsigned nb2 = (len + 255u) / 256u;
    for (unsigned batch = 0; batch < nb2; ++batch) {
        unsigned i = batch * 256u + t;
        bool act = (i < len);
        unsigned p = act ? buf[start + i] : 0u;
        unsigned v = act ? (p >> 24) : 255u;           // sentinel (valid keys < 128)
        unsigned long long m = match_key<8>(v);
        unsigned before = (unsigned)__popcll(m & lmask);
        unsigned total  = (unsigned)__popcll(m);
        int leader = __ffsll(m) - 1;
        unsigned base0 = 0;
        #pragma unroll
        for (int w2 = 0; w2 < 4; ++w2) {
            if (w == w2 && act && before == 0u) { base0 = run[v]; run[v] = base0 + total; }
            __syncthreads();
        }
        base0 = __shfl(base0, leader, 64);
        if (act) csr[start + off[v] + base0 + before] = p & 0xFFFFFFu;
    }
}

// One wave per row: new[r] = sum_j lab[col_j] * 31^(d-1-j)  (mod 2^32).
// Per-lane start power once, then multiply by 31^-64 per stride step.
__global__ void wl_prop(const unsigned* __restrict__ col_csr, const unsigned* __restrict__ rs,
                        const unsigned* __restrict__ deg, const unsigned* __restrict__ lin,
                        unsigned* __restrict__ lout, int n) {
    int r = (int)((blockIdx.x * blockDim.x + threadIdx.x) >> 6);
    int lane = threadIdx.x & 63;
    if (r >= n) return;
    unsigned start = rs[r], d = deg[r];
    unsigned acc = 0;
    if ((unsigned)lane < d) {
        unsigned p = dpow31(d - 1u - (unsigned)lane);
        for (unsigned j = (unsigned)lane; j < d; j += 64u) {
            acc += lin[col_csr[start + j]] * p;
            p *= INV31_64;
        }
    }
    #pragma unroll
    for (int off = 32; off > 0; off >>= 1) acc += __shfl_xor(acc, off, 64);
    if (lane == 0) lout[r] = acc;
}

__global__ void wl_write_out(const unsigned* __restrict__ l0, const unsigned* __restrict__ l1,
                             const unsigned* __restrict__ l2, const unsigned* __restrict__ l3,
                             int* __restrict__ out, int n) {
    int i = blockIdx.x * blockDim.x + threadIdx.x;
    if (i >= n) return;
    int a0 = (int)l0[i], a1 = (int)l1[i], a2 = (int)l2[i], a3 = (int)l3[i];
    out[i]         = a3;   // labels3 (final)
    out[n + i]     = a0;   // labels0
    out[2 * n + i] = a1;   // labels1
    out[3 * n + i] = a2;   // labels2
    out[4 * n + i] = a3;   // labels3
}

extern "C" void kernel_launch(void* const* d_in, const int* in_sizes, int n_in,
                              void* d_out, int out_size, void* d_ws, size_t ws_size,
                              hipStream_t stream) {
    const float* x  = (const float*)d_in[0];
    const int*   ei = (const int*)d_in[1];
    int* out = (int*)d_out;

    const int N = in_sizes[0] / WL_D;
    const int E = in_sizes[1] / 2;
    const int nchunks  = (E + CHUNK - 1) / CHUNK;
    const int nbuckets = (N + BROWS - 1) / BROWS;
    const int L = nbuckets * nchunks;          // 782*782 = 611,524 for N=100k,E=3.2M
    const int nb = (L + 1023) / 1024;          // 598 <= 1024

    // workspace layout (uint32 units) — everything written before read, no memset
    unsigned* ws   = (unsigned*)d_ws;
    unsigned* lab0 = ws;               // N
    unsigned* lab1 = lab0 + N;         // N
    unsigned* lab2 = lab1 + N;         // N
    unsigned* lab3 = lab2 + N;         // N
    unsigned* rs   = lab3 + N;         // N
    unsigned* deg  = rs + N;           // N
    unsigned* bs   = deg + N;          // 1024
    unsigned* hist = bs + 1024;        // L   (block-scanned in place; +bs at use sites)
    unsigned* buf  = hist + L;         // E   (bucket-ordered packed (rl<<24)|col)
    unsigned* csr  = buf + E;          // E   (final: cols in edge order per row)

    const int BT = 256;
    int gridN = (N + BT - 1) / BT;
    int gridW = (N + 3) / 4;                   // wave-per-row kernels

    wl_argmax<<<gridW, BT, 0, stream>>>(x, lab0, N);

    wl_msd_hist<<<nchunks, BT, 0, stream>>>(ei, hist, E, nchunks, nbuckets);
    wl_scan1<<<nb, 1024, 0, stream>>>(hist, hist, bs, L);
    wl_scan2<<<1, 1024, 0, stream>>>(bs, nb);
    wl_msd_scatter<<<nchunks, BT, 0, stream>>>(ei, hist, bs, buf, E, nchunks, nbuckets);
    wl_bucket_sort<<<nbuckets, BT, 0, stream>>>(buf, hist, bs, csr, rs, deg, N, E, nchunks, nbuckets);

    wl_prop<<<gridW, BT, 0, stream>>>(csr, rs, deg, lab0, lab1, N);
    wl_prop<<<gridW, BT, 0, stream>>>(csr, rs, deg, lab1, lab2, N);
    wl_prop<<<gridW, BT, 0, stream>>>(csr, rs, deg, lab2, lab3, N);

    wl_write_out<<<gridN, BT, 0, stream>>>(lab0, lab1, lab2, lab3, out, N);
}

// Round 7
// 302.345 us; speedup vs baseline: 4.2011x; 1.0252x over previous
//
#include <hip/hip_runtime.h>
#include <hip/hip_bf16.h>

// WeisfeilerLehman: labels0 = argmax(x, -1); 3x ordered polynomial hash over edges.
// All arithmetic mod 2^32 (uint32 wrap) == reference int64 truncated to int32.
// R7: R6 design (big chunks E/256 -> 64B scatter runs; per-(bucket,wave) LDS
//     cursors, barrier-free stable scatter) with the h2 zero-init bug fixed
//     (strided loop: 512 LDS words, 256 threads) and nbat clamped >= 0.

#define WL_D 128
#define NCHUNK 256          // chunks == blocks for MSD pass (1 per CU)
#define MSDW 8              // waves per MSD scatter block (512 threads)
#define BROWS 128           // rows per bucket; bucket = row >> 7, rl = row & 127
#define BBITS 7
#define NBMAX 1024          // max buckets supported (N <= 131072)

constexpr unsigned cpow(unsigned b, unsigned e) {
    unsigned p = 1;
    while (e) { if (e & 1u) p *= b; b *= b; e >>= 1u; }
    return p;
}
constexpr unsigned cinv31() {           // Newton: inverse of 31 mod 2^32
    unsigned x = 1;
    for (int i = 0; i < 6; ++i) x *= 2u - 31u * x;
    return x;
}
constexpr unsigned INV31_64 = cpow(cinv31(), 64);   // 31^-64 mod 2^32

__device__ inline unsigned dpow31(unsigned e) {
    unsigned p = 1, b = 31u;
    while (e) { if (e & 1u) p *= b; b *= b; e >>= 1u; }
    return p;
}

// mask of lanes whose low BITS bits of v match mine (inactive lanes use a
// sentinel outside the valid key range so they never match active lanes)
template <int BITS>
__device__ inline unsigned long long match_key(unsigned v) {
    unsigned long long m = ~0ull;
    #pragma unroll
    for (int b = 0; b < BITS; ++b) {
        unsigned long long s = __ballot((v >> b) & 1u);
        m &= ((v >> b) & 1u) ? s : ~s;
    }
    return m;
}

__global__ void wl_argmax(const float* __restrict__ x, unsigned* __restrict__ lab0, int n) {
    int wave = (int)((blockIdx.x * blockDim.x + threadIdx.x) >> 6);
    int lane = threadIdx.x & 63;
    if (wave >= n) return;
    const float* xr = x + (size_t)wave * WL_D;
    float v0 = xr[lane];
    float v1 = xr[lane + 64];
    float bv; int bi;
    if (v1 > v0) { bv = v1; bi = lane + 64; } else { bv = v0; bi = lane; }
    #pragma unroll
    for (int off = 32; off > 0; off >>= 1) {
        float ov = __shfl_down(bv, off, 64);
        int   oi = __shfl_down(bi, off, 64);
        if (ov > bv || (ov == bv && oi < bi)) { bv = ov; bi = oi; }
    }
    if (lane == 0) lab0[wave] = (unsigned)bi;
}

// ---- two-level exclusive scan (1024-wide level 1; level 2 folded at use sites) ----
__global__ void wl_scan1(const unsigned* __restrict__ in, unsigned* __restrict__ out,
                         unsigned* __restrict__ bsums, int n) {
    __shared__ unsigned tmp[1024];
    int i = blockIdx.x * 1024 + threadIdx.x;
    unsigned v = (i < n) ? in[i] : 0u;
    tmp[threadIdx.x] = v;
    __syncthreads();
    for (int off = 1; off < 1024; off <<= 1) {
        unsigned t = (threadIdx.x >= (unsigned)off) ? tmp[threadIdx.x - off] : 0u;
        __syncthreads();
        tmp[threadIdx.x] += t;
        __syncthreads();
    }
    if (i < n) out[i] = tmp[threadIdx.x] - v;   // exclusive within block
    if (threadIdx.x == 1023) bsums[blockIdx.x] = tmp[1023];
}

__global__ void wl_scan2(unsigned* __restrict__ bsums, int nb) {
    __shared__ unsigned tmp[1024];
    int t = threadIdx.x;
    unsigned v = (t < nb) ? bsums[t] : 0u;
    tmp[t] = v;
    __syncthreads();
    for (int off = 1; off < 1024; off <<= 1) {
        unsigned s = (t >= off) ? tmp[t - off] : 0u;
        __syncthreads();
        tmp[t] += s;
        __syncthreads();
    }
    if (t < nb) bsums[t] = tmp[t] - v;          // exclusive
}

// ---- MSD pass 1: per-chunk histogram over buckets, layout hist[bucket][chunk] ----
__global__ void wl_msd_hist(const int* __restrict__ ei, unsigned* __restrict__ hist,
                            int E, int chunk, int nbuckets) {
    __shared__ unsigned h[NBMAX];
    int c = blockIdx.x;
    for (int i = threadIdx.x; i < nbuckets; i += 256) h[i] = 0;
    __syncthreads();
    int base = c * chunk;
    int lim = min(base + chunk, E);
    for (int e = base + threadIdx.x; e < lim; e += 256)
        atomicAdd(&h[((unsigned)ei[e]) >> BBITS], 1u);   // LDS atomic
    __syncthreads();
    for (int b = threadIdx.x; b < nbuckets; b += 256)
        hist[(size_t)b * NCHUNK + c] = h[b];
}

// ---- MSD pass 2: stable scatter of packed (rl<<24)|col into bucket order ----
// Per-wave contiguous sub-chunks; per-(wave,bucket) cursors in LDS; no atomics,
// 2 barriers total. Stability: wave sub-ranges are in edge order; cursors are
// seeded in wave order; in-wave ranks via ballot-match are in lane (edge) order.
__global__ void __launch_bounds__(512)
wl_msd_scatter(const int* __restrict__ ei, const unsigned* __restrict__ choff,
               const unsigned* __restrict__ bs, unsigned* __restrict__ buf,
               int E, int chunk, int nbuckets) {
    __shared__ unsigned wbase[MSDW][NBMAX];
    int c = blockIdx.x, t = threadIdx.x;
    int lane = t & 63, w = t >> 6;
    for (int i = t; i < MSDW * NBMAX; i += 512) ((unsigned*)wbase)[i] = 0u;
    __syncthreads();
    int sub   = (chunk + MSDW - 1) / MSDW;
    int wbeg  = c * chunk + w * sub;
    int wend  = min(wbeg + sub, min(c * chunk + chunk, E));
    int nbat  = (wbeg < wend) ? ((wend - wbeg + 63) >> 6) : 0;
    unsigned long long lmask = (1ull << lane) - 1ull;
    // pass A: per-wave bucket counts (leader-lane plain RMW, lockstep-safe)
    for (int bt = 0; bt < nbat; ++bt) {
        int e = wbeg + bt * 64 + lane;
        bool act = (e < wend);
        unsigned v = act ? (((unsigned)ei[e]) >> BBITS) : (NBMAX - 1u);
        unsigned long long m = match_key<10>(v);
        unsigned before = (unsigned)__popcll(m & lmask);
        unsigned total  = (unsigned)__popcll(m);
        if (act && before == 0u) wbase[w][v] += total;
    }
    __syncthreads();
    // seed cursors: global base for (bucket, wave) in wave order
    for (int v = t; v < nbuckets; v += 512) {
        size_t idx = (size_t)v * NCHUNK + c;
        unsigned g = choff[idx] + bs[idx >> 10];
        #pragma unroll
        for (int w2 = 0; w2 < MSDW; ++w2) {
            unsigned cnt = wbase[w2][v];
            wbase[w2][v] = g;
            g += cnt;
        }
    }
    __syncthreads();
    // pass B: rank + scatter, barrier-free (each wave owns its cursor column)
    for (int bt = 0; bt < nbat; ++bt) {
        int e = wbeg + bt * 64 + lane;
        bool act = (e < wend);
        unsigned r   = act ? (unsigned)ei[e] : 0u;
        unsigned col = act ? (unsigned)ei[(size_t)E + e] : 0u;
        unsigned v = act ? (r >> BBITS) : (NBMAX - 1u);
        unsigned long long m = match_key<10>(v);
        unsigned before = (unsigned)__popcll(m & lmask);
        unsigned total  = (unsigned)__popcll(m);
        int leader = __ffsll(m) - 1;
        unsigned base0 = 0;
        if (act && before == 0u) { base0 = wbase[w][v]; wbase[w][v] = base0 + total; }
        base0 = __shfl(base0, leader, 64);
        if (act) buf[base0 + before] = ((r & (BROWS - 1u)) << 24) | col;
    }
}

// ---- per-bucket stable counting sort by rl; emits rs, deg, ordered col-CSR ----
// Same per-wave-cursor structure; 3 barriers total.
__global__ void wl_bucket_sort(const unsigned* __restrict__ buf, const unsigned* __restrict__ choff,
                               const unsigned* __restrict__ bs, unsigned* __restrict__ csr,
                               unsigned* __restrict__ rs_g, unsigned* __restrict__ deg_g,
                               int N, int E, int nbuckets) {
    __shared__ unsigned h2[4][BROWS];
    __shared__ unsigned off[BROWS];
    int b = blockIdx.x, t = threadIdx.x;
    int lane = t & 63, w = t >> 6;
    size_t i0 = (size_t)b * NCHUNK;
    unsigned start = choff[i0] + bs[i0 >> 10];
    unsigned end;
    if (b + 1 < nbuckets) { size_t i1 = (size_t)(b + 1) * NCHUNK; end = choff[i1] + bs[i1 >> 10]; }
    else end = (unsigned)E;
    unsigned len = end - start;
    for (int i = t; i < 4 * BROWS; i += 256) ((unsigned*)h2)[i] = 0u;   // FIXED: full init
    __syncthreads();
    unsigned sub  = (len + 3u) / 4u;
    unsigned wbeg = w * sub;
    unsigned wend = min(wbeg + sub, len);
    int nbat = (wbeg < wend) ? (int)((wend - wbeg + 63u) >> 6) : 0;
    unsigned long long lmask = (1ull << lane) - 1ull;
    // pass A: per-wave rl counts
    for (int bt = 0; bt < nbat; ++bt) {
        unsigned i = wbeg + (unsigned)(bt * 64 + lane);
        bool act = (i < wend);
        unsigned v = act ? (buf[start + i] >> 24) : 255u;
        unsigned long long m = match_key<8>(v);
        unsigned before = (unsigned)__popcll(m & lmask);
        unsigned total  = (unsigned)__popcll(m);
        if (act && before == 0u) h2[w][v] += total;
    }
    __syncthreads();
    // deg + exclusive scan over rl
    unsigned hv = 0;
    if (t < BROWS) {
        hv = h2[0][t] + h2[1][t] + h2[2][t] + h2[3][t];
        off[t] = hv;
    }
    __syncthreads();
    for (int o = 1; o < BROWS; o <<= 1) {
        unsigned s = (t < BROWS && t >= o) ? off[t - o] : 0u;
        __syncthreads();
        if (t < BROWS) off[t] += s;
        __syncthreads();
    }
    if (t < BROWS) {
        unsigned excl = off[t] - hv;
        int row = b * BROWS + t;
        if (row < N) { rs_g[row] = start + excl; deg_g[row] = hv; }
        unsigned g = start + excl;
        #pragma unroll
        for (int w2 = 0; w2 < 4; ++w2) {
            unsigned cnt = h2[w2][t];
            h2[w2][t] = g;
            g += cnt;
        }
    }
    __syncthreads();
    // pass B: rank + scatter into final CSR slice, barrier-free
    for (int bt = 0; bt < nbat; ++bt) {
        unsigned i = wbeg + (unsigned)(bt * 64 + lane);
        bool act = (i < wend);
        unsigned p = act ? buf[start + i] : 0u;
        unsigned v = act ? (p >> 24) : 255u;
        unsigned long long m = match_key<8>(v);
        unsigned before = (unsigned)__popcll(m & lmask);
        unsigned total  = (unsigned)__popcll(m);
        int leader = __ffsll(m) - 1;
        unsigned base0 = 0;
        if (act && before == 0u) { base0 = h2[w][v]; h2[w][v] = base0 + total; }
        base0 = __shfl(base0, leader, 64);
        if (act) csr[base0 + before] = p & 0xFFFFFFu;
    }
}

// One wave per row: new[r] = sum_j lab[col_j] * 31^(d-1-j)  (mod 2^32).
__global__ void wl_prop(const unsigned* __restrict__ col_csr, const unsigned* __restrict__ rs,
                        const unsigned* __restrict__ deg, const unsigned* __restrict__ lin,
                        unsigned* __restrict__ lout, int n) {
    int r = (int)((blockIdx.x * blockDim.x + threadIdx.x) >> 6);
    int lane = threadIdx.x & 63;
    if (r >= n) return;
    unsigned start = rs[r], d = deg[r];
    unsigned acc = 0;
    if ((unsigned)lane < d) {
        unsigned p = dpow31(d - 1u - (unsigned)lane);
        for (unsigned j = (unsigned)lane; j < d; j += 64u) {
            acc += lin[col_csr[start + j]] * p;
            p *= INV31_64;
        }
    }
    #pragma unroll
    for (int off = 32; off > 0; off >>= 1) acc += __shfl_xor(acc, off, 64);
    if (lane == 0) lout[r] = acc;
}

__global__ void wl_write_out(const unsigned* __restrict__ l0, const unsigned* __restrict__ l1,
                             const unsigned* __restrict__ l2, const unsigned* __restrict__ l3,
                             int* __restrict__ out, int n) {
    int i = blockIdx.x * blockDim.x + threadIdx.x;
    if (i >= n) return;
    int a0 = (int)l0[i], a1 = (int)l1[i], a2 = (int)l2[i], a3 = (int)l3[i];
    out[i]         = a3;   // labels3 (final)
    out[n + i]     = a0;   // labels0
    out[2 * n + i] = a1;   // labels1
    out[3 * n + i] = a2;   // labels2
    out[4 * n + i] = a3;   // labels3
}

extern "C" void kernel_launch(void* const* d_in, const int* in_sizes, int n_in,
                              void* d_out, int out_size, void* d_ws, size_t ws_size,
                              hipStream_t stream) {
    const float* x  = (const float*)d_in[0];
    const int*   ei = (const int*)d_in[1];
    int* out = (int*)d_out;

    const int N = in_sizes[0] / WL_D;
    const int E = in_sizes[1] / 2;
    const int chunk    = (E + NCHUNK - 1) / NCHUNK;    // 12500 for E=3.2M
    const int nbuckets = (N + BROWS - 1) / BROWS;      // 782 for N=100k
    const int L  = nbuckets * NCHUNK;                  // 200,192 scan length
    const int nb = (L + 1023) / 1024;                  // 196 <= 1024

    // workspace layout (uint32 units) — everything written before read, no memset
    unsigned* ws   = (unsigned*)d_ws;
    unsigned* lab0 = ws;               // N
    unsigned* lab1 = lab0 + N;         // N
    unsigned* lab2 = lab1 + N;         // N
    unsigned* lab3 = lab2 + N;         // N
    unsigned* rs   = lab3 + N;         // N
    unsigned* deg  = rs + N;           // N
    unsigned* bs   = deg + N;          // 1024
    unsigned* hist = bs + 1024;        // L   (block-scanned in place; +bs at use sites)
    unsigned* buf  = hist + L;         // E   (bucket-ordered packed (rl<<24)|col)
    unsigned* csr  = buf + E;          // E   (final: cols in edge order per row)

    const int BT = 256;
    int gridN = (N + BT - 1) / BT;
    int gridW = (N + 3) / 4;                   // wave-per-row kernels

    wl_argmax<<<gridW, BT, 0, stream>>>(x, lab0, N);

    wl_msd_hist<<<NCHUNK, BT, 0, stream>>>(ei, hist, E, chunk, nbuckets);
    wl_scan1<<<nb, 1024, 0, stream>>>(hist, hist, bs, L);
    wl_scan2<<<1, 1024, 0, stream>>>(bs, nb);
    wl_msd_scatter<<<NCHUNK, 512, 0, stream>>>(ei, hist, bs, buf, E, chunk, nbuckets);
    wl_bucket_sort<<<nbuckets, BT, 0, stream>>>(buf, hist, bs, csr, rs, deg, N, E, nbuckets);

    wl_prop<<<gridW, BT, 0, stream>>>(csr, rs, deg, lab0, lab1, N);
    wl_prop<<<gridW, BT, 0, stream>>>(csr, rs, deg, lab1, lab2, N);
    wl_prop<<<gridW, BT, 0, stream>>>(csr, rs, deg, lab2, lab3, N);

    wl_write_out<<<gridN, BT, 0, stream>>>(lab0, lab1, lab2, lab3, out, N);
}